// Round 5
// baseline (1711.561 us; speedup 1.0000x reference)
//
#include <hip/hip_runtime.h>
#include <hip/hip_fp16.h>
#include <math.h>

#define N_NODES 100000
#define N_EDGES 600000
#define NB_SCAN ((N_NODES + 1023) / 1024)   // 98 scan blocks of 1024

// ===========================================================================
// CSR build: counting sort of edges by dst (once per launch).
// ===========================================================================
__global__ void hist_k(const int* __restrict__ dst, int* __restrict__ counts,
                       int* __restrict__ rank)
{
    int e = blockIdx.x * 256 + threadIdx.x;
    if (e < N_EDGES) rank[e] = atomicAdd(&counts[dst[e]], 1);
}

__global__ void scan_a_k(const int* __restrict__ counts, int* __restrict__ row_ptr,
                         int* __restrict__ blockSums)
{
    __shared__ int s[256];
    const int t = threadIdx.x;
    const int base = blockIdx.x * 1024 + t * 4;
    int c[4];
#pragma unroll
    for (int j = 0; j < 4; ++j) c[j] = (base + j < N_NODES) ? counts[base + j] : 0;
    const int tot = c[0] + c[1] + c[2] + c[3];
    s[t] = tot;
    __syncthreads();
    for (int off = 1; off < 256; off <<= 1) {
        int v = (t >= off) ? s[t - off] : 0;
        __syncthreads();
        s[t] += v;
        __syncthreads();
    }
    int run = s[t] - tot;
#pragma unroll
    for (int j = 0; j < 4; ++j) {
        if (base + j < N_NODES) row_ptr[base + j] = run;
        run += c[j];
    }
    if (t == 255) blockSums[blockIdx.x] = s[255];
}

__global__ void scan_b_k(const int* __restrict__ blockSums, int* __restrict__ blockOffs)
{
    if (threadIdx.x == 0) {
        int run = 0;
        for (int b = 0; b < NB_SCAN; ++b) { blockOffs[b] = run; run += blockSums[b]; }
    }
}

__global__ void scan_c_k(int* __restrict__ row_ptr, const int* __restrict__ blockOffs)
{
    int i = blockIdx.x * 256 + threadIdx.x;
    if (i < N_NODES) row_ptr[i] += blockOffs[i >> 10];
    if (i == 0) row_ptr[N_NODES] = N_EDGES;
}

__global__ void scatter_k(const int* __restrict__ src, const int* __restrict__ dst,
                          const int* __restrict__ row_ptr, const int* __restrict__ rank,
                          int* __restrict__ perm, int* __restrict__ src_sorted)
{
    int e = blockIdx.x * 256 + threadIdx.x;
    if (e < N_EDGES) {
        int pos = row_ptr[dst[e]] + rank[e];
        perm[pos] = e;
        src_sorted[pos] = src[e];
    }
}

// ===========================================================================
// Edge linear (per conv): e_s[i*128+c] = fp16( ef[perm[i]] @ We[:,c] + be[c] )
// Pure streaming: fully independent iterations, grid-stride over slots,
// We column in 32 VGPRs (amortized over ~70 slots/thread). No dependent chains
// feeding anything — the compiler pipelines the 8 float4 ef loads freely.
// ===========================================================================
__global__ __launch_bounds__(256) void edge_lin_k(
    const float* __restrict__ ef, const int* __restrict__ perm,
    const float* __restrict__ We, const float* __restrict__ be,
    __half* __restrict__ e_s)
{
    const int c  = threadIdx.x & 127;
    const int sl = threadIdx.x >> 7;

    float we[32];
#pragma unroll
    for (int d = 0; d < 32; ++d) we[d] = We[d * 128 + c];
    const float bec = be[c];

    const int stride = gridDim.x * 2;
    for (int i = blockIdx.x * 2 + sl; i < N_EDGES; i += stride) {
        const int e = perm[i];
        const float4* p = (const float4*)(ef + (size_t)e * 32);
        float acc = bec;
#pragma unroll
        for (int d4 = 0; d4 < 8; ++d4) {
            const float4 v = p[d4];
            acc = fmaf(v.x, we[4 * d4 + 0], acc);
            acc = fmaf(v.y, we[4 * d4 + 1], acc);
            acc = fmaf(v.z, we[4 * d4 + 2], acc);
            acc = fmaf(v.w, we[4 * d4 + 3], acc);
        }
        e_s[(size_t)i * 128 + c] = __float2half(acc);
    }
}

// ===========================================================================
// Slim CSR aggregation: agg[n] = sum_i relu(x[src_s[i]] + e_s[i])
// Per-edge body is 2 loads + add/relu/acc. src_s[i] is wave-uniform (s_load).
// 8-wide batches with clamp-to-last predication: 8 independent x-gathers in
// flight per wave — the only latency leg left.
// ===========================================================================
__global__ __launch_bounds__(256) void agg_slim_k(
    const float* __restrict__ x, const int* __restrict__ src_s,
    const __half* __restrict__ e_s, const int* __restrict__ row_ptr,
    float* __restrict__ agg)
{
    const int c    = threadIdx.x & 127;
    const int slot = threadIdx.x >> 7;
    const int node = blockIdx.x * 2 + slot;
    if (node >= N_NODES) return;

    const int start = row_ptr[node];
    const int end   = row_ptr[node + 1];
    float acc = 0.f;

    for (int i = start; i < end; i += 8) {
        const int last = end - 1;
        int idx[8];
#pragma unroll
        for (int b = 0; b < 8; ++b) {
            const int ib = i + b;
            idx[b] = (ib < end) ? ib : last;
        }
        int ss[8];
#pragma unroll
        for (int b = 0; b < 8; ++b) ss[b] = src_s[idx[b]];   // wave-uniform -> s_load
        float xs[8];
#pragma unroll
        for (int b = 0; b < 8; ++b) xs[b] = x[(size_t)ss[b] * 128 + c];
        float es[8];
#pragma unroll
        for (int b = 0; b < 8; ++b) es[b] = __half2float(e_s[(size_t)idx[b] * 128 + c]);
#pragma unroll
        for (int b = 0; b < 8; ++b) {
            const float v = fmaxf(xs[b] + es[b], 0.f);
            acc += (i + b < end) ? v : 0.f;
        }
    }
    agg[(size_t)node * 128 + c] = acc;
}

// ---------------------------------------------------------------------------
// Fused 2-layer node MLP (unchanged):
//   t = act1((xin + agg) @ Wa + ba);  out = actF(t @ Wb + bb)
// ---------------------------------------------------------------------------
template <int NOUT, bool TANH1, bool TANHF, bool ADDAGG>
__global__ __launch_bounds__(256, 4) void mlp2_k(
    const float* __restrict__ xin, const float* __restrict__ agg,
    const float* __restrict__ Wa, const float* __restrict__ ba,
    const float* __restrict__ Wb, const float* __restrict__ bb,
    float* __restrict__ out)
{
    __shared__ float hT[128][68];
    const int tid = threadIdx.x;
    const int n0  = blockIdx.x * 64;

    {
        const int mrow = tid >> 5;
        const int kq   = tid & 31;
#pragma unroll
        for (int g = 0; g < 8; ++g) {
            const int row  = g * 8 + mrow;
            const int node = n0 + row;
            float4 v = make_float4(0.f, 0.f, 0.f, 0.f);
            if (node < N_NODES) {
                v = *(const float4*)(xin + (size_t)node * 128 + kq * 4);
                if (ADDAGG) {
                    float4 a = *(const float4*)(agg + (size_t)node * 128 + kq * 4);
                    v.x += a.x; v.y += a.y; v.z += a.z; v.w += a.w;
                }
            }
            hT[kq * 4 + 0][row] = v.x;
            hT[kq * 4 + 1][row] = v.y;
            hT[kq * 4 + 2][row] = v.z;
            hT[kq * 4 + 3][row] = v.w;
        }
    }
    __syncthreads();

    const int ty4 = (tid >> 4) * 4;
    const int tx4 = (tid & 15) * 4;

    float acc[2][4][4];
#pragma unroll
    for (int p = 0; p < 2; ++p)
#pragma unroll
        for (int i = 0; i < 4; ++i)
#pragma unroll
            for (int j = 0; j < 4; ++j) acc[p][i][j] = 0.f;

#pragma unroll 4
    for (int k = 0; k < 128; ++k) {
        const float4 av = *(const float4*)&hT[k][ty4];
#pragma unroll
        for (int p = 0; p < 2; ++p) {
            const float4 bv = *(const float4*)(Wa + (size_t)k * 128 + p * 64 + tx4);
            acc[p][0][0] = fmaf(av.x, bv.x, acc[p][0][0]);
            acc[p][0][1] = fmaf(av.x, bv.y, acc[p][0][1]);
            acc[p][0][2] = fmaf(av.x, bv.z, acc[p][0][2]);
            acc[p][0][3] = fmaf(av.x, bv.w, acc[p][0][3]);
            acc[p][1][0] = fmaf(av.y, bv.x, acc[p][1][0]);
            acc[p][1][1] = fmaf(av.y, bv.y, acc[p][1][1]);
            acc[p][1][2] = fmaf(av.y, bv.z, acc[p][1][2]);
            acc[p][1][3] = fmaf(av.y, bv.w, acc[p][1][3]);
            acc[p][2][0] = fmaf(av.z, bv.x, acc[p][2][0]);
            acc[p][2][1] = fmaf(av.z, bv.y, acc[p][2][1]);
            acc[p][2][2] = fmaf(av.z, bv.z, acc[p][2][2]);
            acc[p][2][3] = fmaf(av.z, bv.w, acc[p][2][3]);
            acc[p][3][0] = fmaf(av.w, bv.x, acc[p][3][0]);
            acc[p][3][1] = fmaf(av.w, bv.y, acc[p][3][1]);
            acc[p][3][2] = fmaf(av.w, bv.z, acc[p][3][2]);
            acc[p][3][3] = fmaf(av.w, bv.w, acc[p][3][3]);
        }
    }
    __syncthreads();

#pragma unroll
    for (int p = 0; p < 2; ++p) {
        const int cb = p * 64 + tx4;
        const float4 bias = *(const float4*)(ba + cb);
        const float bj[4] = {bias.x, bias.y, bias.z, bias.w};
#pragma unroll
        for (int i = 0; i < 4; ++i) {
#pragma unroll
            for (int j = 0; j < 4; ++j) {
                float v = acc[p][i][j] + bj[j];
                v = TANH1 ? tanhf(v) : fmaxf(v, 0.f);
                hT[cb + j][ty4 + i] = v;
            }
        }
    }
    __syncthreads();

#pragma unroll
    for (int p = 0; p < NOUT / 64; ++p) {
        float a2[4][4];
#pragma unroll
        for (int i = 0; i < 4; ++i)
#pragma unroll
            for (int j = 0; j < 4; ++j) a2[i][j] = 0.f;

#pragma unroll 4
        for (int k = 0; k < 128; ++k) {
            const float4 av = *(const float4*)&hT[k][ty4];
            const float4 bv = *(const float4*)(Wb + (size_t)k * NOUT + p * 64 + tx4);
            a2[0][0] = fmaf(av.x, bv.x, a2[0][0]);
            a2[0][1] = fmaf(av.x, bv.y, a2[0][1]);
            a2[0][2] = fmaf(av.x, bv.z, a2[0][2]);
            a2[0][3] = fmaf(av.x, bv.w, a2[0][3]);
            a2[1][0] = fmaf(av.y, bv.x, a2[1][0]);
            a2[1][1] = fmaf(av.y, bv.y, a2[1][1]);
            a2[1][2] = fmaf(av.y, bv.z, a2[1][2]);
            a2[1][3] = fmaf(av.y, bv.w, a2[1][3]);
            a2[2][0] = fmaf(av.z, bv.x, a2[2][0]);
            a2[2][1] = fmaf(av.z, bv.y, a2[2][1]);
            a2[2][2] = fmaf(av.z, bv.z, a2[2][2]);
            a2[2][3] = fmaf(av.z, bv.w, a2[2][3]);
            a2[3][0] = fmaf(av.w, bv.x, a2[3][0]);
            a2[3][1] = fmaf(av.w, bv.y, a2[3][1]);
            a2[3][2] = fmaf(av.w, bv.z, a2[3][2]);
            a2[3][3] = fmaf(av.w, bv.w, a2[3][3]);
        }
        const int cb = p * 64 + tx4;
        const float4 bias = *(const float4*)(bb + cb);
#pragma unroll
        for (int i = 0; i < 4; ++i) {
            const int node = n0 + ty4 + i;
            if (node < N_NODES) {
                float4 o;
                o.x = a2[i][0] + bias.x;
                o.y = a2[i][1] + bias.y;
                o.z = a2[i][2] + bias.z;
                o.w = a2[i][3] + bias.w;
                if (TANHF) { o.x = tanhf(o.x); o.y = tanhf(o.y); o.z = tanhf(o.z); o.w = tanhf(o.w); }
                *(float4*)(out + (size_t)node * NOUT + cb) = o;
            }
        }
    }
}

// ---------------------------------------------------------------------------
extern "C" void kernel_launch(void* const* d_in, const int* in_sizes, int n_in,
                              void* d_out, int out_size, void* d_ws, size_t ws_size,
                              hipStream_t stream)
{
    const float* x   = (const float*)d_in[0];
    const int*   ei  = (const int*)  d_in[1];
    const float* ef  = (const float*)d_in[2];
    const float* We1 = (const float*)d_in[3];
    const float* be1 = (const float*)d_in[4];
    const float* W1a = (const float*)d_in[5];
    const float* b1a = (const float*)d_in[6];
    const float* W1b = (const float*)d_in[7];
    const float* b1b = (const float*)d_in[8];
    const float* We2 = (const float*)d_in[9];
    const float* be2 = (const float*)d_in[10];
    const float* W2a = (const float*)d_in[11];
    const float* b2a = (const float*)d_in[12];
    const float* W2b = (const float*)d_in[13];
    const float* b2b = (const float*)d_in[14];
    const float* Wf1 = (const float*)d_in[15];
    const float* bf1 = (const float*)d_in[16];
    const float* Wf2 = (const float*)d_in[17];
    const float* bf2 = (const float*)d_in[18];
    float* out = (float*)d_out;

    const int* src = ei;             // edge_index[0]
    const int* dst = ei + N_EDGES;   // edge_index[1]

    // ---- workspace layout (~261 MB) ----
    float*  agg     = (float*)d_ws;                      // N*128 f
    float*  h       = agg + (size_t)N_NODES * 128;       // N*128 f
    int*    row_ptr = (int*)(h + (size_t)N_NODES * 128); // N+8 (padded)
    int*    perm    = row_ptr + (N_NODES + 8);           // E
    int*    src_s   = perm + N_EDGES;                    // E
    __half* e_s     = (__half*)(src_s + N_EDGES);        // E*128 halves (per-conv scratch)
    // sort temporaries overlaid on agg (dead before agg_slim_k writes agg):
    int* counts    = (int*)agg;                          // N
    int* rank      = counts + N_NODES;                   // E
    int* blockSums = rank + N_EDGES;                     // NB_SCAN
    int* blockOffs = blockSums + NB_SCAN;                // NB_SCAN

    const int mlpGrid = (N_NODES + 63) / 64;
    const int aggGrid = (N_NODES + 1) / 2;
    const int eGrid   = (N_EDGES + 255) / 256;
    const int nGrid   = (N_NODES + 255) / 256;
    const int elGrid  = 4096;   // grid-stride: ~73 slots/thread, amortizes We regs

    // ---- build sorted CSR (same work every call; edge_index is fixed) ----
    hipMemsetAsync(counts, 0, (size_t)N_NODES * sizeof(int), stream);
    hist_k   <<<eGrid,   256, 0, stream>>>(dst, counts, rank);
    scan_a_k <<<NB_SCAN, 256, 0, stream>>>(counts, row_ptr, blockSums);
    scan_b_k <<<1,        64, 0, stream>>>(blockSums, blockOffs);
    scan_c_k <<<nGrid,   256, 0, stream>>>(row_ptr, blockOffs);
    scatter_k<<<eGrid,   256, 0, stream>>>(src, dst, row_ptr, rank, perm, src_s);

    // ---- conv1 ----
    edge_lin_k<<<elGrid,  256, 0, stream>>>(ef, perm, We1, be1, e_s);
    agg_slim_k<<<aggGrid, 256, 0, stream>>>(x, src_s, e_s, row_ptr, agg);
    mlp2_k<128, false, true, true><<<mlpGrid, 256, 0, stream>>>(x, agg, W1a, b1a, W1b, b1b, h);

    // ---- conv2 ----
    edge_lin_k<<<elGrid,  256, 0, stream>>>(ef, perm, We2, be2, e_s);
    agg_slim_k<<<aggGrid, 256, 0, stream>>>(h, src_s, e_s, row_ptr, agg);
    mlp2_k<128, false, true, true><<<mlpGrid, 256, 0, stream>>>(h, agg, W2a, b2a, W2b, b2b, h);

    // ---- head ----
    mlp2_k<64, true, false, false><<<mlpGrid, 256, 0, stream>>>(h, nullptr, Wf1, bf1, Wf2, bf2, out);
}

// Round 6
// 887.701 us; speedup vs baseline: 1.9281x; 1.9281x over previous
//
#include <hip/hip_runtime.h>
#include <hip/hip_fp16.h>
#include <math.h>

#define N_NODES 100000
#define N_EDGES 600000
#define NB_SCAN ((N_NODES + 1023) / 1024)   // 98 scan blocks of 1024

// ===========================================================================
// CSR build: counting sort of edges by dst (once per launch).
// ===========================================================================
__global__ void hist_k(const int* __restrict__ dst, int* __restrict__ counts,
                       int* __restrict__ rank)
{
    int e = blockIdx.x * 256 + threadIdx.x;
    if (e < N_EDGES) rank[e] = atomicAdd(&counts[dst[e]], 1);
}

__global__ void scan_a_k(const int* __restrict__ counts, int* __restrict__ row_ptr,
                         int* __restrict__ blockSums)
{
    __shared__ int s[256];
    const int t = threadIdx.x;
    const int base = blockIdx.x * 1024 + t * 4;
    int c[4];
#pragma unroll
    for (int j = 0; j < 4; ++j) c[j] = (base + j < N_NODES) ? counts[base + j] : 0;
    const int tot = c[0] + c[1] + c[2] + c[3];
    s[t] = tot;
    __syncthreads();
    for (int off = 1; off < 256; off <<= 1) {
        int v = (t >= off) ? s[t - off] : 0;
        __syncthreads();
        s[t] += v;
        __syncthreads();
    }
    int run = s[t] - tot;
#pragma unroll
    for (int j = 0; j < 4; ++j) {
        if (base + j < N_NODES) row_ptr[base + j] = run;
        run += c[j];
    }
    if (t == 255) blockSums[blockIdx.x] = s[255];
}

__global__ void scan_b_k(const int* __restrict__ blockSums, int* __restrict__ blockOffs)
{
    if (threadIdx.x == 0) {
        int run = 0;
        for (int b = 0; b < NB_SCAN; ++b) { blockOffs[b] = run; run += blockSums[b]; }
    }
}

__global__ void scan_c_k(int* __restrict__ row_ptr, const int* __restrict__ blockOffs)
{
    int i = blockIdx.x * 256 + threadIdx.x;
    if (i < N_NODES) row_ptr[i] += blockOffs[i >> 10];
    if (i == 0) row_ptr[N_NODES] = N_EDGES;
}

__global__ void scatter_k(const int* __restrict__ src, const int* __restrict__ dst,
                          const int* __restrict__ row_ptr, const int* __restrict__ rank,
                          int* __restrict__ perm, int* __restrict__ src_sorted)
{
    int e = blockIdx.x * 256 + threadIdx.x;
    if (e < N_EDGES) {
        int pos = row_ptr[dst[e]] + rank[e];
        perm[pos] = e;
        src_sorted[pos] = src[e];
    }
}

// ===========================================================================
// Edge linear as LDS-tiled GEMM (per conv):
//   e_s[i*128+c] = fp16( ef[perm[i]] @ We[:,c] + be[c] ),  64 slots per block.
// The 64 gathered ef rows are fetched by 512 INDEPENDENT per-lane float4
// loads (2/thread, all in flight) -> LDS; We staged in LDS (16 KB); then a
// register-tiled [64x32]@[32x128] produces the fp16 outputs. This replaces
// round-5's per-slot serial perm->ef chain (512 us, latency-bound).
// N_EDGES = 9375 * 64 exactly -> no tail handling.
// ===========================================================================
__global__ __launch_bounds__(256) void edge_lin_gemm_k(
    const float* __restrict__ ef, const int* __restrict__ perm,
    const float* __restrict__ We, const float* __restrict__ be,
    __half* __restrict__ e_s)
{
    __shared__ float sEf[64][36];    // 64 gathered rows, pad 36 (2-way max on write)
    __shared__ float sWe[32][128];   // 16 KB
    const int t  = threadIdx.x;
    const int i0 = blockIdx.x * 64;

    // ---- stage We (flat 1024 float4, 4 per thread) ----
    {
        const float4* W4 = (const float4*)We;
        float4* S4 = (float4*)(&sWe[0][0]);
#pragma unroll
        for (int j = 0; j < 4; ++j) S4[t + j * 256] = W4[t + j * 256];
    }
    // ---- gather 64 ef rows: 2 independent float4 loads per thread ----
    {
        const int row = t >> 2;          // 0..63
        const int q   = t & 3;           // float4 index q and q+4
        const int e   = perm[i0 + row];  // 4 threads share one perm read (L1)
        const float4* p = (const float4*)(ef + (size_t)e * 32);
        const float4 v0 = p[q];
        const float4 v1 = p[q + 4];
        *(float4*)(&sEf[row][q * 4])       = v0;
        *(float4*)(&sEf[row][(q + 4) * 4]) = v1;
    }
    __syncthreads();

    // ---- compute: thread -> 4 cols c..c+3, 8 slots s0..s0+7 ----
    const int c  = (t & 31) * 4;
    const int s0 = (t >> 5) * 8;
    float acc[8][4];
    const float4 bv = *(const float4*)(be + c);
#pragma unroll
    for (int s = 0; s < 8; ++s) {
        acc[s][0] = bv.x; acc[s][1] = bv.y; acc[s][2] = bv.z; acc[s][3] = bv.w;
    }

#pragma unroll 8
    for (int k = 0; k < 32; ++k) {
        const float4 w = *(const float4*)(&sWe[k][c]);
#pragma unroll
        for (int s = 0; s < 8; ++s) {
            const float a = sEf[s0 + s][k];   // uniform per half-wave -> broadcast
            acc[s][0] = fmaf(a, w.x, acc[s][0]);
            acc[s][1] = fmaf(a, w.y, acc[s][1]);
            acc[s][2] = fmaf(a, w.z, acc[s][2]);
            acc[s][3] = fmaf(a, w.w, acc[s][3]);
        }
    }

    // ---- store fp16 (lanes of a slot-group write consecutive 8B -> coalesced)
#pragma unroll
    for (int s = 0; s < 8; ++s) {
        __half2 h01 = __floats2half2_rn(acc[s][0], acc[s][1]);
        __half2 h23 = __floats2half2_rn(acc[s][2], acc[s][3]);
        __half2* d2 = (__half2*)(e_s + (size_t)(i0 + s0 + s) * 128 + c);
        d2[0] = h01;
        d2[1] = h23;
    }
}

// ===========================================================================
// Slim CSR aggregation (unchanged from round 5 — no longer the bottleneck):
//   agg[n] = sum_i relu(x[src_s[i]] + e_s[i])
// ===========================================================================
__global__ __launch_bounds__(256) void agg_slim_k(
    const float* __restrict__ x, const int* __restrict__ src_s,
    const __half* __restrict__ e_s, const int* __restrict__ row_ptr,
    float* __restrict__ agg)
{
    const int c    = threadIdx.x & 127;
    const int slot = threadIdx.x >> 7;
    const int node = blockIdx.x * 2 + slot;
    if (node >= N_NODES) return;

    const int start = row_ptr[node];
    const int end   = row_ptr[node + 1];
    float acc = 0.f;

    for (int i = start; i < end; i += 8) {
        const int last = end - 1;
        int idx[8];
#pragma unroll
        for (int b = 0; b < 8; ++b) {
            const int ib = i + b;
            idx[b] = (ib < end) ? ib : last;
        }
        int ss[8];
#pragma unroll
        for (int b = 0; b < 8; ++b) ss[b] = src_s[idx[b]];
        float xs[8];
#pragma unroll
        for (int b = 0; b < 8; ++b) xs[b] = x[(size_t)ss[b] * 128 + c];
        float es[8];
#pragma unroll
        for (int b = 0; b < 8; ++b) es[b] = __half2float(e_s[(size_t)idx[b] * 128 + c]);
#pragma unroll
        for (int b = 0; b < 8; ++b) {
            const float v = fmaxf(xs[b] + es[b], 0.f);
            acc += (i + b < end) ? v : 0.f;
        }
    }
    agg[(size_t)node * 128 + c] = acc;
}

// ---------------------------------------------------------------------------
// Fused 2-layer node MLP (unchanged):
//   t = act1((xin + agg) @ Wa + ba);  out = actF(t @ Wb + bb)
// ---------------------------------------------------------------------------
template <int NOUT, bool TANH1, bool TANHF, bool ADDAGG>
__global__ __launch_bounds__(256, 4) void mlp2_k(
    const float* __restrict__ xin, const float* __restrict__ agg,
    const float* __restrict__ Wa, const float* __restrict__ ba,
    const float* __restrict__ Wb, const float* __restrict__ bb,
    float* __restrict__ out)
{
    __shared__ float hT[128][68];
    const int tid = threadIdx.x;
    const int n0  = blockIdx.x * 64;

    {
        const int mrow = tid >> 5;
        const int kq   = tid & 31;
#pragma unroll
        for (int g = 0; g < 8; ++g) {
            const int row  = g * 8 + mrow;
            const int node = n0 + row;
            float4 v = make_float4(0.f, 0.f, 0.f, 0.f);
            if (node < N_NODES) {
                v = *(const float4*)(xin + (size_t)node * 128 + kq * 4);
                if (ADDAGG) {
                    float4 a = *(const float4*)(agg + (size_t)node * 128 + kq * 4);
                    v.x += a.x; v.y += a.y; v.z += a.z; v.w += a.w;
                }
            }
            hT[kq * 4 + 0][row] = v.x;
            hT[kq * 4 + 1][row] = v.y;
            hT[kq * 4 + 2][row] = v.z;
            hT[kq * 4 + 3][row] = v.w;
        }
    }
    __syncthreads();

    const int ty4 = (tid >> 4) * 4;
    const int tx4 = (tid & 15) * 4;

    float acc[2][4][4];
#pragma unroll
    for (int p = 0; p < 2; ++p)
#pragma unroll
        for (int i = 0; i < 4; ++i)
#pragma unroll
            for (int j = 0; j < 4; ++j) acc[p][i][j] = 0.f;

#pragma unroll 4
    for (int k = 0; k < 128; ++k) {
        const float4 av = *(const float4*)&hT[k][ty4];
#pragma unroll
        for (int p = 0; p < 2; ++p) {
            const float4 bv = *(const float4*)(Wa + (size_t)k * 128 + p * 64 + tx4);
            acc[p][0][0] = fmaf(av.x, bv.x, acc[p][0][0]);
            acc[p][0][1] = fmaf(av.x, bv.y, acc[p][0][1]);
            acc[p][0][2] = fmaf(av.x, bv.z, acc[p][0][2]);
            acc[p][0][3] = fmaf(av.x, bv.w, acc[p][0][3]);
            acc[p][1][0] = fmaf(av.y, bv.x, acc[p][1][0]);
            acc[p][1][1] = fmaf(av.y, bv.y, acc[p][1][1]);
            acc[p][1][2] = fmaf(av.y, bv.z, acc[p][1][2]);
            acc[p][1][3] = fmaf(av.y, bv.w, acc[p][1][3]);
            acc[p][2][0] = fmaf(av.z, bv.x, acc[p][2][0]);
            acc[p][2][1] = fmaf(av.z, bv.y, acc[p][2][1]);
            acc[p][2][2] = fmaf(av.z, bv.z, acc[p][2][2]);
            acc[p][2][3] = fmaf(av.z, bv.w, acc[p][2][3]);
            acc[p][3][0] = fmaf(av.w, bv.x, acc[p][3][0]);
            acc[p][3][1] = fmaf(av.w, bv.y, acc[p][3][1]);
            acc[p][3][2] = fmaf(av.w, bv.z, acc[p][3][2]);
            acc[p][3][3] = fmaf(av.w, bv.w, acc[p][3][3]);
        }
    }
    __syncthreads();

#pragma unroll
    for (int p = 0; p < 2; ++p) {
        const int cb = p * 64 + tx4;
        const float4 bias = *(const float4*)(ba + cb);
        const float bj[4] = {bias.x, bias.y, bias.z, bias.w};
#pragma unroll
        for (int i = 0; i < 4; ++i) {
#pragma unroll
            for (int j = 0; j < 4; ++j) {
                float v = acc[p][i][j] + bj[j];
                v = TANH1 ? tanhf(v) : fmaxf(v, 0.f);
                hT[cb + j][ty4 + i] = v;
            }
        }
    }
    __syncthreads();

#pragma unroll
    for (int p = 0; p < NOUT / 64; ++p) {
        float a2[4][4];
#pragma unroll
        for (int i = 0; i < 4; ++i)
#pragma unroll
            for (int j = 0; j < 4; ++j) a2[i][j] = 0.f;

#pragma unroll 4
        for (int k = 0; k < 128; ++k) {
            const float4 av = *(const float4*)&hT[k][ty4];
            const float4 bv = *(const float4*)(Wb + (size_t)k * NOUT + p * 64 + tx4);
            a2[0][0] = fmaf(av.x, bv.x, a2[0][0]);
            a2[0][1] = fmaf(av.x, bv.y, a2[0][1]);
            a2[0][2] = fmaf(av.x, bv.z, a2[0][2]);
            a2[0][3] = fmaf(av.x, bv.w, a2[0][3]);
            a2[1][0] = fmaf(av.y, bv.x, a2[1][0]);
            a2[1][1] = fmaf(av.y, bv.y, a2[1][1]);
            a2[1][2] = fmaf(av.y, bv.z, a2[1][2]);
            a2[1][3] = fmaf(av.y, bv.w, a2[1][3]);
            a2[2][0] = fmaf(av.z, bv.x, a2[2][0]);
            a2[2][1] = fmaf(av.z, bv.y, a2[2][1]);
            a2[2][2] = fmaf(av.z, bv.z, a2[2][2]);
            a2[2][3] = fmaf(av.z, bv.w, a2[2][3]);
            a2[3][0] = fmaf(av.w, bv.x, a2[3][0]);
            a2[3][1] = fmaf(av.w, bv.y, a2[3][1]);
            a2[3][2] = fmaf(av.w, bv.z, a2[3][2]);
            a2[3][3] = fmaf(av.w, bv.w, a2[3][3]);
        }
        const int cb = p * 64 + tx4;
        const float4 bias = *(const float4*)(bb + cb);
#pragma unroll
        for (int i = 0; i < 4; ++i) {
            const int node = n0 + ty4 + i;
            if (node < N_NODES) {
                float4 o;
                o.x = a2[i][0] + bias.x;
                o.y = a2[i][1] + bias.y;
                o.z = a2[i][2] + bias.z;
                o.w = a2[i][3] + bias.w;
                if (TANHF) { o.x = tanhf(o.x); o.y = tanhf(o.y); o.z = tanhf(o.z); o.w = tanhf(o.w); }
                *(float4*)(out + (size_t)node * NOUT + cb) = o;
            }
        }
    }
}

// ---------------------------------------------------------------------------
extern "C" void kernel_launch(void* const* d_in, const int* in_sizes, int n_in,
                              void* d_out, int out_size, void* d_ws, size_t ws_size,
                              hipStream_t stream)
{
    const float* x   = (const float*)d_in[0];
    const int*   ei  = (const int*)  d_in[1];
    const float* ef  = (const float*)d_in[2];
    const float* We1 = (const float*)d_in[3];
    const float* be1 = (const float*)d_in[4];
    const float* W1a = (const float*)d_in[5];
    const float* b1a = (const float*)d_in[6];
    const float* W1b = (const float*)d_in[7];
    const float* b1b = (const float*)d_in[8];
    const float* We2 = (const float*)d_in[9];
    const float* be2 = (const float*)d_in[10];
    const float* W2a = (const float*)d_in[11];
    const float* b2a = (const float*)d_in[12];
    const float* W2b = (const float*)d_in[13];
    const float* b2b = (const float*)d_in[14];
    const float* Wf1 = (const float*)d_in[15];
    const float* bf1 = (const float*)d_in[16];
    const float* Wf2 = (const float*)d_in[17];
    const float* bf2 = (const float*)d_in[18];
    float* out = (float*)d_out;

    const int* src = ei;             // edge_index[0]
    const int* dst = ei + N_EDGES;   // edge_index[1]

    // ---- workspace layout (~261 MB) ----
    float*  agg     = (float*)d_ws;                      // N*128 f
    float*  h       = agg + (size_t)N_NODES * 128;       // N*128 f
    int*    row_ptr = (int*)(h + (size_t)N_NODES * 128); // N+8 (padded)
    int*    perm    = row_ptr + (N_NODES + 8);           // E
    int*    src_s   = perm + N_EDGES;                    // E
    __half* e_s     = (__half*)(src_s + N_EDGES);        // E*128 halves (per-conv scratch)
    // sort temporaries overlaid on agg (dead before agg_slim_k writes agg):
    int* counts    = (int*)agg;                          // N
    int* rank      = counts + N_NODES;                   // E
    int* blockSums = rank + N_EDGES;                     // NB_SCAN
    int* blockOffs = blockSums + NB_SCAN;                // NB_SCAN

    const int mlpGrid = (N_NODES + 63) / 64;
    const int aggGrid = (N_NODES + 1) / 2;
    const int eGrid   = (N_EDGES + 255) / 256;
    const int nGrid   = (N_NODES + 255) / 256;
    const int elGrid  = N_EDGES / 64;   // 9375, exact

    // ---- build sorted CSR (same work every call; edge_index is fixed) ----
    hipMemsetAsync(counts, 0, (size_t)N_NODES * sizeof(int), stream);
    hist_k   <<<eGrid,   256, 0, stream>>>(dst, counts, rank);
    scan_a_k <<<NB_SCAN, 256, 0, stream>>>(counts, row_ptr, blockSums);
    scan_b_k <<<1,        64, 0, stream>>>(blockSums, blockOffs);
    scan_c_k <<<nGrid,   256, 0, stream>>>(row_ptr, blockOffs);
    scatter_k<<<eGrid,   256, 0, stream>>>(src, dst, row_ptr, rank, perm, src_s);

    // ---- conv1 ----
    edge_lin_gemm_k<<<elGrid, 256, 0, stream>>>(ef, perm, We1, be1, e_s);
    agg_slim_k<<<aggGrid, 256, 0, stream>>>(x, src_s, e_s, row_ptr, agg);
    mlp2_k<128, false, true, true><<<mlpGrid, 256, 0, stream>>>(x, agg, W1a, b1a, W1b, b1b, h);

    // ---- conv2 ----
    edge_lin_gemm_k<<<elGrid, 256, 0, stream>>>(ef, perm, We2, be2, e_s);
    agg_slim_k<<<aggGrid, 256, 0, stream>>>(h, src_s, e_s, row_ptr, agg);
    mlp2_k<128, false, true, true><<<mlpGrid, 256, 0, stream>>>(h, agg, W2a, b2a, W2b, b2b, h);

    // ---- head ----
    mlp2_k<64, true, false, false><<<mlpGrid, 256, 0, stream>>>(h, nullptr, Wf1, bf1, Wf2, bf2, out);
}

// Round 7
// 834.540 us; speedup vs baseline: 2.0509x; 1.0637x over previous
//
#include <hip/hip_runtime.h>
#include <hip/hip_fp16.h>
#include <math.h>

#define N_NODES 100000
#define N_EDGES 600000
#define NB_SCAN ((N_NODES + 1023) / 1024)   // 98 scan blocks of 1024

typedef unsigned short u16;
typedef __bf16 bf16x8 __attribute__((ext_vector_type(8)));
typedef float  f32x4  __attribute__((ext_vector_type(4)));

__device__ __forceinline__ u16 f2bf(float f) {
    union { float f; unsigned u; } c; c.f = f;
    unsigned u = c.u + 0x7fffu + ((c.u >> 16) & 1u);   // RNE
    return (u16)(u >> 16);
}
__device__ __forceinline__ float bf2f(u16 h) {
    union { unsigned u; float f; } c; c.u = ((unsigned)h) << 16;
    return c.f;
}

// ===========================================================================
// CSR build: counting sort of edges by dst (once per launch).
// ===========================================================================
__global__ void hist_k(const int* __restrict__ dst, int* __restrict__ counts,
                       int* __restrict__ rank)
{
    int e = blockIdx.x * 256 + threadIdx.x;
    if (e < N_EDGES) rank[e] = atomicAdd(&counts[dst[e]], 1);
}

__global__ void scan_a_k(const int* __restrict__ counts, int* __restrict__ row_ptr,
                         int* __restrict__ blockSums)
{
    __shared__ int s[256];
    const int t = threadIdx.x;
    const int base = blockIdx.x * 1024 + t * 4;
    int c[4];
#pragma unroll
    for (int j = 0; j < 4; ++j) c[j] = (base + j < N_NODES) ? counts[base + j] : 0;
    const int tot = c[0] + c[1] + c[2] + c[3];
    s[t] = tot;
    __syncthreads();
    for (int off = 1; off < 256; off <<= 1) {
        int v = (t >= off) ? s[t - off] : 0;
        __syncthreads();
        s[t] += v;
        __syncthreads();
    }
    int run = s[t] - tot;
#pragma unroll
    for (int j = 0; j < 4; ++j) {
        if (base + j < N_NODES) row_ptr[base + j] = run;
        run += c[j];
    }
    if (t == 255) blockSums[blockIdx.x] = s[255];
}

__global__ void scan_b_k(const int* __restrict__ blockSums, int* __restrict__ blockOffs)
{
    if (threadIdx.x == 0) {
        int run = 0;
        for (int b = 0; b < NB_SCAN; ++b) { blockOffs[b] = run; run += blockSums[b]; }
    }
}

__global__ void scan_c_k(int* __restrict__ row_ptr, const int* __restrict__ blockOffs)
{
    int i = blockIdx.x * 256 + threadIdx.x;
    if (i < N_NODES) row_ptr[i] += blockOffs[i >> 10];
    if (i == 0) row_ptr[N_NODES] = N_EDGES;
}

__global__ void scatter_k(const int* __restrict__ src, const int* __restrict__ dst,
                          const int* __restrict__ row_ptr, const int* __restrict__ rank,
                          int* __restrict__ perm, int* __restrict__ src_sorted)
{
    int e = blockIdx.x * 256 + threadIdx.x;
    if (e < N_EDGES) {
        int pos = row_ptr[dst[e]] + rank[e];
        perm[pos] = e;
        src_sorted[pos] = src[e];
    }
}

// ===========================================================================
// Weight prep (once per launch): fp32 W[k][n] -> transposed bf16 hi/lo WT[n][k].
// Layout in wT (u16): matrix m in {0..4} at m*32768 (hi 16384 then lo 16384);
// matrix 5 (Wfc2, 128x64) at 163840 (hi 8192 then lo 8192).
// ===========================================================================
__global__ void wprep_k(const float* __restrict__ W1a, const float* __restrict__ W1b,
                        const float* __restrict__ W2a, const float* __restrict__ W2b,
                        const float* __restrict__ Wf1, const float* __restrict__ Wf2,
                        u16* __restrict__ wT)
{
    int idx = blockIdx.x * 256 + threadIdx.x;
    if (idx >= 90112) return;
    int m, local;
    if      (idx < 16384) { m = 0; local = idx; }
    else if (idx < 32768) { m = 1; local = idx - 16384; }
    else if (idx < 49152) { m = 2; local = idx - 32768; }
    else if (idx < 65536) { m = 3; local = idx - 49152; }
    else if (idx < 81920) { m = 4; local = idx - 65536; }
    else                  { m = 5; local = idx - 81920; }
    const int N = (m == 5) ? 64 : 128;
    const float* src = (m == 0) ? W1a : (m == 1) ? W1b : (m == 2) ? W2a
                     : (m == 3) ? W2b : (m == 4) ? Wf1 : Wf2;
    const int k = local / N, n = local % N;
    const float w = src[k * N + n];
    const u16 hi = f2bf(w);
    const u16 lo = f2bf(w - bf2f(hi));
    const int base = m * 32768;
    const int sz   = (m == 5) ? 8192 : 16384;
    wT[base + n * 128 + k]      = hi;
    wT[base + sz + n * 128 + k] = lo;
}

// ===========================================================================
// Edge linear as LDS-tiled GEMM (per conv) — unchanged from round 6.
// ===========================================================================
__global__ __launch_bounds__(256) void edge_lin_gemm_k(
    const float* __restrict__ ef, const int* __restrict__ perm,
    const float* __restrict__ We, const float* __restrict__ be,
    __half* __restrict__ e_s)
{
    __shared__ float sEf[64][36];
    __shared__ float sWe[32][128];
    const int t  = threadIdx.x;
    const int i0 = blockIdx.x * 64;

    {
        const float4* W4 = (const float4*)We;
        float4* S4 = (float4*)(&sWe[0][0]);
#pragma unroll
        for (int j = 0; j < 4; ++j) S4[t + j * 256] = W4[t + j * 256];
    }
    {
        const int row = t >> 2;
        const int q   = t & 3;
        const int e   = perm[i0 + row];
        const float4* p = (const float4*)(ef + (size_t)e * 32);
        const float4 v0 = p[q];
        const float4 v1 = p[q + 4];
        *(float4*)(&sEf[row][q * 4])       = v0;
        *(float4*)(&sEf[row][(q + 4) * 4]) = v1;
    }
    __syncthreads();

    const int c  = (t & 31) * 4;
    const int s0 = (t >> 5) * 8;
    float acc[8][4];
    const float4 bv = *(const float4*)(be + c);
#pragma unroll
    for (int s = 0; s < 8; ++s) {
        acc[s][0] = bv.x; acc[s][1] = bv.y; acc[s][2] = bv.z; acc[s][3] = bv.w;
    }

#pragma unroll 8
    for (int k = 0; k < 32; ++k) {
        const float4 w = *(const float4*)(&sWe[k][c]);
#pragma unroll
        for (int s = 0; s < 8; ++s) {
            const float a = sEf[s0 + s][k];
            acc[s][0] = fmaf(a, w.x, acc[s][0]);
            acc[s][1] = fmaf(a, w.y, acc[s][1]);
            acc[s][2] = fmaf(a, w.z, acc[s][2]);
            acc[s][3] = fmaf(a, w.w, acc[s][3]);
        }
    }

#pragma unroll
    for (int s = 0; s < 8; ++s) {
        __half2 h01 = __floats2half2_rn(acc[s][0], acc[s][1]);
        __half2 h23 = __floats2half2_rn(acc[s][2], acc[s][3]);
        __half2* d2 = (__half2*)(e_s + (size_t)(i0 + s0 + s) * 128 + c);
        d2[0] = h01;
        d2[1] = h23;
    }
}

// ===========================================================================
// Slim CSR aggregation — unchanged from round 6.
// ===========================================================================
__global__ __launch_bounds__(256) void agg_slim_k(
    const float* __restrict__ x, const int* __restrict__ src_s,
    const __half* __restrict__ e_s, const int* __restrict__ row_ptr,
    float* __restrict__ agg)
{
    const int c    = threadIdx.x & 127;
    const int slot = threadIdx.x >> 7;
    const int node = blockIdx.x * 2 + slot;
    if (node >= N_NODES) return;

    const int start = row_ptr[node];
    const int end   = row_ptr[node + 1];
    float acc = 0.f;

    for (int i = start; i < end; i += 8) {
        const int last = end - 1;
        int idx[8];
#pragma unroll
        for (int b = 0; b < 8; ++b) {
            const int ib = i + b;
            idx[b] = (ib < end) ? ib : last;
        }
        int ss[8];
#pragma unroll
        for (int b = 0; b < 8; ++b) ss[b] = src_s[idx[b]];
        float xs[8];
#pragma unroll
        for (int b = 0; b < 8; ++b) xs[b] = x[(size_t)ss[b] * 128 + c];
        float es[8];
#pragma unroll
        for (int b = 0; b < 8; ++b) es[b] = __half2float(e_s[(size_t)idx[b] * 128 + c]);
#pragma unroll
        for (int b = 0; b < 8; ++b) {
            const float v = fmaxf(xs[b] + es[b], 0.f);
            acc += (i + b < end) ? v : 0.f;
        }
    }
    agg[(size_t)node * 128 + c] = acc;
}

// ===========================================================================
// Fused 2-layer node MLP via bf16 hi/lo split MFMA (16x16x32):
//   t   = act1((xin + agg) @ Wa + ba);  out = actF(t @ Wb + bb)
// Each product W*x ~ hi*hi + hi*lo + lo*hi (3 MFMAs) => ~fp32 precision.
// 64-node tile staged as bf16 hi/lo in LDS [64][136] (pad keeps b128 reads
// ~2-way). Wave w owns rows [16w,16w+16): A-frags, t-writes and layer-B reads
// are wave-private => single barrier after staging. B-frags stream from
// transposed bf16 weights in global (L1/L2 resident).
// A-layout: A[m=lane&15][k=quad*8+j]; C/D: col=lane&15, row=quad*4+reg.
// ===========================================================================
template <int NT2, bool TANH1, bool TANHF, bool ADDAGG>
__global__ __launch_bounds__(256, 4) void mlp2_mfma_k(
    const float* __restrict__ xin, const float* __restrict__ agg,
    const u16* __restrict__ WaT_hi, const u16* __restrict__ WaT_lo,
    const float* __restrict__ ba,
    const u16* __restrict__ WbT_hi, const u16* __restrict__ WbT_lo,
    const float* __restrict__ bb,
    float* __restrict__ out)
{
    __shared__ u16 sHi[64][136];
    __shared__ u16 sLo[64][136];
    const int tid = threadIdx.x;
    const int n0  = blockIdx.x * 64;

    // ---- stage tile: fp32 (xin + agg) -> bf16 hi/lo in LDS ----
    {
        const int mrow = tid >> 5, kq = tid & 31;
#pragma unroll
        for (int g = 0; g < 8; ++g) {
            const int row  = g * 8 + mrow;
            const int node = n0 + row;
            float4 v = make_float4(0.f, 0.f, 0.f, 0.f);
            if (node < N_NODES) {
                v = *(const float4*)(xin + (size_t)node * 128 + kq * 4);
                if (ADDAGG) {
                    float4 a4 = *(const float4*)(agg + (size_t)node * 128 + kq * 4);
                    v.x += a4.x; v.y += a4.y; v.z += a4.z; v.w += a4.w;
                }
            }
            const u16 h0 = f2bf(v.x), h1 = f2bf(v.y), h2 = f2bf(v.z), h3 = f2bf(v.w);
            const u16 l0 = f2bf(v.x - bf2f(h0)), l1 = f2bf(v.y - bf2f(h1));
            const u16 l2 = f2bf(v.z - bf2f(h2)), l3 = f2bf(v.w - bf2f(h3));
            *(uint2*)&sHi[row][kq * 4] =
                make_uint2((unsigned)h0 | ((unsigned)h1 << 16), (unsigned)h2 | ((unsigned)h3 << 16));
            *(uint2*)&sLo[row][kq * 4] =
                make_uint2((unsigned)l0 | ((unsigned)l1 << 16), (unsigned)l2 | ((unsigned)l3 << 16));
        }
    }
    __syncthreads();

    const int lane = tid & 63, wave = tid >> 6;
    const int quad = lane >> 4, col = lane & 15;
    const int mb = wave * 16;

    // ---- layer A: a-frags (wave-private rows) into regs ----
    bf16x8 aHi[4], aLo[4];
#pragma unroll
    for (int k0 = 0; k0 < 4; ++k0) {
        aHi[k0] = *(const bf16x8*)&sHi[mb + col][k0 * 32 + quad * 8];
        aLo[k0] = *(const bf16x8*)&sLo[mb + col][k0 * 32 + quad * 8];
    }
    float bAv[8];
#pragma unroll
    for (int nt = 0; nt < 8; ++nt) bAv[nt] = ba[nt * 16 + col];

#pragma unroll 2
    for (int nt = 0; nt < 8; ++nt) {
        f32x4 acc = {bAv[nt], bAv[nt], bAv[nt], bAv[nt]};
#pragma unroll
        for (int k0 = 0; k0 < 4; ++k0) {
            const size_t off = (size_t)(nt * 16 + col) * 128 + k0 * 32 + quad * 8;
            const bf16x8 bHi = *(const bf16x8*)(WaT_hi + off);
            const bf16x8 bLo = *(const bf16x8*)(WaT_lo + off);
            acc = __builtin_amdgcn_mfma_f32_16x16x32_bf16(aHi[k0], bHi, acc, 0, 0, 0);
            acc = __builtin_amdgcn_mfma_f32_16x16x32_bf16(aHi[k0], bLo, acc, 0, 0, 0);
            acc = __builtin_amdgcn_mfma_f32_16x16x32_bf16(aLo[k0], bHi, acc, 0, 0, 0);
        }
        // act1 + re-split t into the same (wave-private) LDS rows
#pragma unroll
        for (int r = 0; r < 4; ++r) {
            float v = TANH1 ? tanhf(acc[r]) : fmaxf(acc[r], 0.f);
            const u16 hv = f2bf(v);
            const u16 lv = f2bf(v - bf2f(hv));
            sHi[mb + quad * 4 + r][nt * 16 + col] = hv;
            sLo[mb + quad * 4 + r][nt * 16 + col] = lv;
        }
    }

    // ---- layer B: t-frags from own rows (same-wave RAW ordered by waitcnt) ----
    bf16x8 tHi[4], tLo[4];
#pragma unroll
    for (int k0 = 0; k0 < 4; ++k0) {
        tHi[k0] = *(const bf16x8*)&sHi[mb + col][k0 * 32 + quad * 8];
        tLo[k0] = *(const bf16x8*)&sLo[mb + col][k0 * 32 + quad * 8];
    }
    constexpr int NOUT = NT2 * 16;
    float bBv[NT2];
#pragma unroll
    for (int nt = 0; nt < NT2; ++nt) bBv[nt] = bb[nt * 16 + col];

#pragma unroll 2
    for (int nt = 0; nt < NT2; ++nt) {
        f32x4 acc = {bBv[nt], bBv[nt], bBv[nt], bBv[nt]};
#pragma unroll
        for (int k0 = 0; k0 < 4; ++k0) {
            const size_t off = (size_t)(nt * 16 + col) * 128 + k0 * 32 + quad * 8;
            const bf16x8 bHi = *(const bf16x8*)(WbT_hi + off);
            const bf16x8 bLo = *(const bf16x8*)(WbT_lo + off);
            acc = __builtin_amdgcn_mfma_f32_16x16x32_bf16(tHi[k0], bHi, acc, 0, 0, 0);
            acc = __builtin_amdgcn_mfma_f32_16x16x32_bf16(tHi[k0], bLo, acc, 0, 0, 0);
            acc = __builtin_amdgcn_mfma_f32_16x16x32_bf16(tLo[k0], bHi, acc, 0, 0, 0);
        }
#pragma unroll
        for (int r = 0; r < 4; ++r) {
            const int node = n0 + mb + quad * 4 + r;
            if (node < N_NODES) {
                float v = acc[r];
                if (TANHF) v = tanhf(v);
                out[(size_t)node * NOUT + nt * 16 + col] = v;
            }
        }
    }
}

// ---------------------------------------------------------------------------
extern "C" void kernel_launch(void* const* d_in, const int* in_sizes, int n_in,
                              void* d_out, int out_size, void* d_ws, size_t ws_size,
                              hipStream_t stream)
{
    const float* x   = (const float*)d_in[0];
    const int*   ei  = (const int*)  d_in[1];
    const float* ef  = (const float*)d_in[2];
    const float* We1 = (const float*)d_in[3];
    const float* be1 = (const float*)d_in[4];
    const float* W1a = (const float*)d_in[5];
    const float* b1a = (const float*)d_in[6];
    const float* W1b = (const float*)d_in[7];
    const float* b1b = (const float*)d_in[8];
    const float* We2 = (const float*)d_in[9];
    const float* be2 = (const float*)d_in[10];
    const float* W2a = (const float*)d_in[11];
    const float* b2a = (const float*)d_in[12];
    const float* W2b = (const float*)d_in[13];
    const float* b2b = (const float*)d_in[14];
    const float* Wf1 = (const float*)d_in[15];
    const float* bf1 = (const float*)d_in[16];
    const float* Wf2 = (const float*)d_in[17];
    const float* bf2 = (const float*)d_in[18];
    float* out = (float*)d_out;

    const int* src = ei;             // edge_index[0]
    const int* dst = ei + N_EDGES;   // edge_index[1]

    // ---- workspace layout (~262 MB) ----
    float*  agg     = (float*)d_ws;                      // N*128 f
    float*  h       = agg + (size_t)N_NODES * 128;       // N*128 f
    int*    row_ptr = (int*)(h + (size_t)N_NODES * 128); // N+8 (padded)
    int*    perm    = row_ptr + (N_NODES + 8);           // E
    int*    src_s   = perm + N_EDGES;                    // E
    __half* e_s     = (__half*)(src_s + N_EDGES);        // E*128 halves
    u16*    wT      = (u16*)(e_s + (size_t)N_EDGES * 128); // 180224 u16 bf16 weights
    // sort temporaries overlaid on agg (dead before agg_slim_k writes agg):
    int* counts    = (int*)agg;                          // N
    int* rank      = counts + N_NODES;                   // E
    int* blockSums = rank + N_EDGES;                     // NB_SCAN
    int* blockOffs = blockSums + NB_SCAN;                // NB_SCAN

    // transposed bf16 weight blocks (hi at +0, lo at +size)
    u16* W1aT = wT;                  // 16384 hi + 16384 lo
    u16* W1bT = wT + 32768;
    u16* W2aT = wT + 65536;
    u16* W2bT = wT + 98304;
    u16* Wf1T = wT + 131072;
    u16* Wf2T = wT + 163840;         // 8192 hi + 8192 lo

    const int mlpGrid = (N_NODES + 63) / 64;
    const int aggGrid = (N_NODES + 1) / 2;
    const int eGrid   = (N_EDGES + 255) / 256;
    const int nGrid   = (N_NODES + 255) / 256;
    const int elGrid  = N_EDGES / 64;   // 9375, exact
    const int wpGrid  = (90112 + 255) / 256;

    // ---- build sorted CSR + bf16 weights (same work every call) ----
    hipMemsetAsync(counts, 0, (size_t)N_NODES * sizeof(int), stream);
    hist_k   <<<eGrid,   256, 0, stream>>>(dst, counts, rank);
    wprep_k  <<<wpGrid,  256, 0, stream>>>(W1a, W1b, W2a, W2b, Wf1, Wf2, wT);
    scan_a_k <<<NB_SCAN, 256, 0, stream>>>(counts, row_ptr, blockSums);
    scan_b_k <<<1,        64, 0, stream>>>(blockSums, blockOffs);
    scan_c_k <<<nGrid,   256, 0, stream>>>(row_ptr, blockOffs);
    scatter_k<<<eGrid,   256, 0, stream>>>(src, dst, row_ptr, rank, perm, src_s);

    // ---- conv1 ----
    edge_lin_gemm_k<<<elGrid, 256, 0, stream>>>(ef, perm, We1, be1, e_s);
    agg_slim_k<<<aggGrid, 256, 0, stream>>>(x, src_s, e_s, row_ptr, agg);
    mlp2_mfma_k<8, false, true, true><<<mlpGrid, 256, 0, stream>>>(
        x, agg, W1aT, W1aT + 16384, b1a, W1bT, W1bT + 16384, b1b, h);

    // ---- conv2 ----
    edge_lin_gemm_k<<<elGrid, 256, 0, stream>>>(ef, perm, We2, be2, e_s);
    agg_slim_k<<<aggGrid, 256, 0, stream>>>(h, src_s, e_s, row_ptr, agg);
    mlp2_mfma_k<8, false, true, true><<<mlpGrid, 256, 0, stream>>>(
        h, agg, W2aT, W2aT + 16384, b2a, W2bT, W2bT + 16384, b2b, h);

    // ---- head ----
    mlp2_mfma_k<4, true, false, false><<<mlpGrid, 256, 0, stream>>>(
        h, nullptr, Wf1T, Wf1T + 16384, bf1, Wf2T, Wf2T + 8192, bf2, out);
}